// Round 7
// baseline (883.057 us; speedup 1.0000x reference)
//
#include <hip/hip_runtime.h>
#include <hip/hip_bf16.h>
#include <cmath>

#define SLOPE 0.2f

typedef __attribute__((ext_vector_type(8))) short bf16x8;
typedef __attribute__((ext_vector_type(4))) float f32x4;
typedef __attribute__((ext_vector_type(2))) float f32x2;

union bfpack { bf16x8 v; unsigned int u[4]; };

__device__ __forceinline__ unsigned short bf16_rne(float x) {
    unsigned int b = __float_as_uint(x);
    b += 0x7FFFu + ((b >> 16) & 1u);
    return (unsigned short)(b >> 16);
}
__device__ __forceinline__ float bf16_tof(unsigned short h) {
    return __uint_as_float(((unsigned int)h) << 16);
}
__device__ __forceinline__ f32x2 splat2(float s) { return (f32x2){s, s}; }

// ---------------------------------------------------------------- preprocessing

__global__ __launch_bounds__(256) void count_deg_kernel(
    const int* __restrict__ dstv, int* __restrict__ deg, int E)
{
    int e = blockIdx.x * 256 + threadIdx.x;
    if (e >= E) return;
    atomicAdd(&deg[dstv[e]], 1);
}

// multi-block exclusive scan over (deg[i]+1), 1024 elems per block
__global__ __launch_bounds__(256) void scanA_kernel(
    const int* __restrict__ deg, int* __restrict__ bsum, int N)
{
    __shared__ int wsum[4];
    int t = threadIdx.x;
    int base = blockIdx.x * 1024 + t * 4;
    int s = 0;
    #pragma unroll
    for (int j = 0; j < 4; ++j) {
        int i = base + j;
        if (i < N) s += deg[i] + 1;
    }
    #pragma unroll
    for (int off = 1; off < 64; off <<= 1) s += __shfl_xor(s, off);
    if ((t & 63) == 0) wsum[t >> 6] = s;
    __syncthreads();
    if (t == 0) bsum[blockIdx.x] = wsum[0] + wsum[1] + wsum[2] + wsum[3];
}

// inclusive scan of nb (<=1024) block sums, in place
__global__ void scanB_kernel(int* __restrict__ bsum, int nb)
{
    __shared__ int wsum[16];
    int t = threadIdx.x, lane = t & 63, w = t >> 6;
    int v = (t < nb) ? bsum[t] : 0;
    #pragma unroll
    for (int off = 1; off < 64; off <<= 1) {
        int u = __shfl_up(v, off);
        if (lane >= off) v += u;
    }
    if (lane == 63) wsum[w] = v;
    __syncthreads();
    int add = 0;
    for (int i = 0; i < w; ++i) add += wsum[i];
    v += add;
    if (t < nb) bsum[t] = v;
}

__global__ __launch_bounds__(256) void scanC_kernel(
    const int* __restrict__ deg, const int* __restrict__ bsum,
    int* __restrict__ rowptr, int N)
{
    __shared__ int wsum[4];
    int t = threadIdx.x, lane = t & 63, w = t >> 6;
    int base = blockIdx.x * 1024 + t * 4;
    int v[4];
    int s = 0;
    #pragma unroll
    for (int j = 0; j < 4; ++j) {
        int i = base + j;
        v[j] = (i < N) ? (deg[i] + 1) : 0;
        s += v[j];
    }
    int incl = s;
    #pragma unroll
    for (int off = 1; off < 64; off <<= 1) {
        int u = __shfl_up(incl, off);
        if (lane >= off) incl += u;
    }
    if (lane == 63) wsum[w] = incl;
    __syncthreads();
    int wadd = 0;
    for (int i = 0; i < w; ++i) wadd += wsum[i];
    int boff = blockIdx.x ? bsum[blockIdx.x - 1] : 0;
    int running = boff + wadd + (incl - s);
    #pragma unroll
    for (int j = 0; j < 4; ++j) {
        int i = base + j;
        running += v[j];
        if (i < N) rowptr[i + 1] = running;
    }
    if (blockIdx.x == 0 && t == 0) rowptr[0] = 0;
}

__global__ __launch_bounds__(256) void fill_csr_kernel(
    const int* __restrict__ srcv, const int* __restrict__ dstv,
    const float* __restrict__ eattr,
    const int* __restrict__ rowptr, int* __restrict__ fill,
    int* __restrict__ col, float* __restrict__ eattr_perm, int E)
{
    int e = blockIdx.x * 256 + threadIdx.x;
    if (e >= E) return;
    int d = dstv[e];
    int pos = rowptr[d] + atomicAdd(&fill[d], 1);
    col[pos] = srcv[e];
    *(float4*)&eattr_perm[(size_t)pos * 4] = *(const float4*)&eattr[(size_t)e * 4];
}

__global__ __launch_bounds__(256) void selfloop_kernel(
    const int* __restrict__ rowptr, const int* __restrict__ deg,
    int* __restrict__ col, float* __restrict__ eattr_perm, int N)
{
    int n = blockIdx.x * 256 + threadIdx.x;
    if (n >= N) return;
    int e0 = rowptr[n], e1 = rowptr[n + 1];
    float4 s = make_float4(0.f, 0.f, 0.f, 0.f);
    for (int e = e0; e < e1 - 1; ++e) {
        float4 a = *(const float4*)&eattr_perm[(size_t)e * 4];
        s.x += a.x; s.y += a.y; s.z += a.z; s.w += a.w;
    }
    float inv = 1.0f / fmaxf((float)deg[n], 1.0f);
    s.x *= inv; s.y *= inv; s.z *= inv; s.w *= inv;
    int pos = e1 - 1;
    col[pos] = n;
    *(float4*)&eattr_perm[(size_t)pos * 4] = s;
}

// W prep: Thi/Tlo[c][k] = bf16 hi/lo split of W[k][c], c in [0,256) = Wl|Wr.
__global__ __launch_bounds__(128) void wprep_kernel(
    const float* __restrict__ Wl, const float* __restrict__ Wr,
    unsigned short* __restrict__ Thi, unsigned short* __restrict__ Tlo)
{
    int c = blockIdx.x;      // 0..255
    int k = threadIdx.x;     // 0..127
    const float* W = (c < 128) ? Wl : Wr;
    float v = W[(size_t)k * 128 + (c & 127)];
    unsigned short h = bf16_rne(v);
    float lo = v - bf16_tof(h);
    Thi[(size_t)c * 128 + k] = h;
    Tlo[(size_t)c * 128 + k] = bf16_rne(lo);
}

// ---------------------------------------------------------------- MFMA GEMM (bf16x3)
// XLH|XRH (both bf16) = H @ [Wl|Wr].  32-row tile, 4 waves (64-col quadrant each),
// launch_bounds(256,4) for latency hiding of the in-loop L2 B-fragment loads.
__global__ __launch_bounds__(256, 4) void gemm_mfma_kernel(
    const float* __restrict__ H,
    const unsigned short* __restrict__ Thi, const unsigned short* __restrict__ Tlo,
    unsigned short* __restrict__ XLH, unsigned short* __restrict__ XRH, int nrows)
{
    __shared__ unsigned short sHi[32 * 128];
    __shared__ unsigned short sLo[32 * 128];
    int t = threadIdx.x;
    int r0 = blockIdx.x * 32;

    #pragma unroll
    for (int i = 0; i < 2; ++i) {
        int idx = t + i * 256;           // 512 = 32 rows * 16 chunks
        int row = idx >> 4, chunk = idx & 15;
        int gr = min(r0 + row, nrows - 1);
        float4 a = *(const float4*)&H[(size_t)gr * 128 + chunk * 8];
        float4 b = *(const float4*)&H[(size_t)gr * 128 + chunk * 8 + 4];
        float v[8] = {a.x, a.y, a.z, a.w, b.x, b.y, b.z, b.w};
        union { bf16x8 v; unsigned short u[8]; } hv, lv;
        #pragma unroll
        for (int j = 0; j < 8; ++j) {
            unsigned short h = bf16_rne(v[j]);
            hv.u[j] = h;
            lv.u[j] = bf16_rne(v[j] - bf16_tof(h));
        }
        int slot = chunk ^ (row & 7);
        *(bf16x8*)&sHi[row * 128 + slot * 8] = hv.v;
        *(bf16x8*)&sLo[row * 128 + slot * 8] = lv.v;
    }
    __syncthreads();

    int w  = t >> 6;
    int l  = t & 63;
    int lr = l & 15;
    int lk = l >> 4;
    int cbase = w * 64;

    f32x4 acc[2][4];
    #pragma unroll
    for (int i = 0; i < 2; ++i)
        #pragma unroll
        for (int j = 0; j < 4; ++j)
            acc[i][j] = (f32x4){0.f, 0.f, 0.f, 0.f};

    #pragma unroll
    for (int k0 = 0; k0 < 128; k0 += 32) {
        bf16x8 ah[2], al[2];
        #pragma unroll
        for (int rt = 0; rt < 2; ++rt) {
            int row = rt * 16 + lr;
            int chunk = (k0 >> 3) + lk;
            int slot = chunk ^ (row & 7);
            ah[rt] = *(const bf16x8*)&sHi[row * 128 + slot * 8];
            al[rt] = *(const bf16x8*)&sLo[row * 128 + slot * 8];
        }
        int k = k0 + lk * 8;
        #pragma unroll
        for (int ct = 0; ct < 4; ++ct) {
            int c = cbase + ct * 16 + lr;
            bf16x8 bh = *(const bf16x8*)&Thi[(size_t)c * 128 + k];
            bf16x8 bl = *(const bf16x8*)&Tlo[(size_t)c * 128 + k];
            #pragma unroll
            for (int rt = 0; rt < 2; ++rt) {
                acc[rt][ct] = __builtin_amdgcn_mfma_f32_16x16x32_bf16(ah[rt], bh, acc[rt][ct], 0, 0, 0);
                acc[rt][ct] = __builtin_amdgcn_mfma_f32_16x16x32_bf16(al[rt], bh, acc[rt][ct], 0, 0, 0);
                acc[rt][ct] = __builtin_amdgcn_mfma_f32_16x16x32_bf16(ah[rt], bl, acc[rt][ct], 0, 0, 0);
            }
        }
    }

    unsigned short* OUT = (w < 2) ? XLH : XRH;
    int ccol0 = (cbase & 127);
    #pragma unroll
    for (int rt = 0; rt < 2; ++rt)
        #pragma unroll
        for (int ct = 0; ct < 4; ++ct) {
            int cc = ccol0 + ct * 16 + lr;
            #pragma unroll
            for (int q = 0; q < 4; ++q) {
                int r = r0 + rt * 16 + lk * 4 + q;
                if (r < nrows) OUT[(size_t)r * 128 + cc] = bf16_rne(acc[rt][ct][q]);
            }
        }
}

// ---------------------------------------------------------------- fused GATv2 attention + aggregation
// wave = 4 consecutive nodes; 4 edges in flight (16 lanes/edge, 8 ch/lane);
// packed-f32 math, defer-max online softmax, 2-deep edge prefetch, bf16 xl/xr.
__global__ __launch_bounds__(256) void gat_agg_kernel(
    const unsigned short* __restrict__ xlh, const unsigned short* __restrict__ xrh,
    const int* __restrict__ rowptr, const int* __restrict__ col,
    const float* __restrict__ eattr_perm,
    const float* __restrict__ We, const float* __restrict__ att, const float* __restrict__ bias,
    float* __restrict__ out, int N, int do_relu)
{
    int w = threadIdx.x >> 6;
    int lane = threadIdx.x & 63;
    int g = lane >> 4;
    int lg = lane & 15;
    int c0 = lg * 8;

    f32x2 at2[4], we2[4][4];
    float bv[8];
    #pragma unroll
    for (int p = 0; p < 4; ++p) at2[p] = (f32x2){att[c0 + 2 * p], att[c0 + 2 * p + 1]};
    #pragma unroll
    for (int j = 0; j < 8; ++j) bv[j] = bias[c0 + j];
    #pragma unroll
    for (int k = 0; k < 4; ++k)
        #pragma unroll
        for (int p = 0; p < 4; ++p)
            we2[k][p] = (f32x2){We[k * 128 + c0 + 2 * p], We[k * 128 + c0 + 2 * p + 1]};

    int nbase = (blockIdx.x * 4 + w) * 4;
    for (int i = 0; i < 4; ++i) {
        int n = nbase + i;
        if (n >= N) return;           // wave-uniform

        f32x2 xr2[4];
        {
            bfpack xrp;
            xrp.v = *(const bf16x8*)&xrh[((size_t)n << 7) + c0];
            #pragma unroll
            for (int p = 0; p < 4; ++p) {
                unsigned int u = xrp.u[p];
                xr2[p] = (f32x2){__uint_as_float(u << 16), __uint_as_float(u & 0xffff0000u)};
            }
        }

        int e0 = rowptr[n], e1 = rowptr[n + 1];
        float m = -INFINITY, den = 0.f;
        f32x2 acc2[4];
        #pragma unroll
        for (int p = 0; p < 4; ++p) acc2[p] = (f32x2){0.f, 0.f};

        auto process = [&](const float4& eav, const bfpack& xv) {
            f32x2 xl2[4];
            #pragma unroll
            for (int p = 0; p < 4; ++p) {
                unsigned int u = xv.u[p];
                xl2[p] = (f32x2){__uint_as_float(u << 16), __uint_as_float(u & 0xffff0000u)};
            }
            f32x2 vd = (f32x2){0.f, 0.f};
            #pragma unroll
            for (int p = 0; p < 4; ++p) {
                f32x2 z = xl2[p] + xr2[p];
                z += splat2(eav.x) * we2[0][p];
                z += splat2(eav.y) * we2[1][p];
                z += splat2(eav.z) * we2[2][p];
                z += splat2(eav.w) * we2[3][p];
                f32x2 zs = splat2(SLOPE) * z;
                f32x2 lz = (f32x2){fmaxf(z.x, zs.x), fmaxf(z.y, zs.y)};
                vd += lz * at2[p];
            }
            float v = vd.x + vd.y;
            v += __shfl_xor(v, 1);
            v += __shfl_xor(v, 2);
            v += __shfl_xor(v, 4);
            v += __shfl_xor(v, 8);

            if (v - m > 8.0f) {
                float scale = __expf(m - v);     // 0 on first edge (m=-inf)
                den = den * scale + 1.0f;
                #pragma unroll
                for (int p = 0; p < 4; ++p) acc2[p] = acc2[p] * splat2(scale) + xl2[p];
                m = v;
            } else {
                float wgt = __expf(v - m);
                den += wgt;
                #pragma unroll
                for (int p = 0; p < 4; ++p) acc2[p] += splat2(wgt) * xl2[p];
            }
        };

        int e = e0 + g;
        float4 ea0 = make_float4(0.f, 0.f, 0.f, 0.f), ea1 = ea0;
        bfpack x0p, x1p;
        x0p.u[0] = x0p.u[1] = x0p.u[2] = x0p.u[3] = 0;
        x1p = x0p;
        if (e < e1) {
            int s = col[e];
            ea0 = *(const float4*)&eattr_perm[(size_t)e * 4];
            x0p.v = *(const bf16x8*)&xlh[((size_t)(unsigned)s << 7) + c0];
        }
        if (e + 4 < e1) {
            int s = col[e + 4];
            ea1 = *(const float4*)&eattr_perm[(size_t)(e + 4) * 4];
            x1p.v = *(const bf16x8*)&xlh[((size_t)(unsigned)s << 7) + c0];
        }

        while (e + 4 < e1) {
            {
                float4 eav = ea0; bfpack xv = x0p;
                int ep = e + 8;
                if (ep < e1) {
                    int s = col[ep];
                    ea0 = *(const float4*)&eattr_perm[(size_t)ep * 4];
                    x0p.v = *(const bf16x8*)&xlh[((size_t)(unsigned)s << 7) + c0];
                }
                process(eav, xv);
            }
            {
                float4 eav = ea1; bfpack xv = x1p;
                int ep = e + 12;
                if (ep < e1) {
                    int s = col[ep];
                    ea1 = *(const float4*)&eattr_perm[(size_t)ep * 4];
                    x1p.v = *(const bf16x8*)&xlh[((size_t)(unsigned)s << 7) + c0];
                }
                process(eav, xv);
            }
            e += 8;
        }
        if (e < e1) process(ea0, x0p);

        // combine 4 groups (differing running maxima)
        float M = fmaxf(m, __shfl_xor(m, 16));
        M = fmaxf(M, __shfl_xor(M, 32));
        float sc = __expf(m - M);        // 0 for empty groups
        float d2 = den * sc;
        d2 += __shfl_xor(d2, 16);
        d2 += __shfl_xor(d2, 32);
        float inv = 1.f / (d2 + 1e-16f);
        float o[8];
        #pragma unroll
        for (int p = 0; p < 4; ++p) {
            float ax = acc2[p].x * sc;
            float ay = acc2[p].y * sc;
            ax += __shfl_xor(ax, 16); ax += __shfl_xor(ax, 32);
            ay += __shfl_xor(ay, 16); ay += __shfl_xor(ay, 32);
            float vx = ax * inv + bv[2 * p];
            float vy = ay * inv + bv[2 * p + 1];
            o[2 * p]     = do_relu ? fmaxf(vx, 0.f) : vx;
            o[2 * p + 1] = do_relu ? fmaxf(vy, 0.f) : vy;
        }
        if (g == 0) {
            *(float4*)&out[((size_t)n << 7) + c0]     = make_float4(o[0], o[1], o[2], o[3]);
            *(float4*)&out[((size_t)n << 7) + c0 + 4] = make_float4(o[4], o[5], o[6], o[7]);
        }
    }
}

// ---------------------------------------------------------------- launch

static inline char* carve(char*& p, size_t bytes) {
    char* r = p;
    p += (bytes + 255) & ~(size_t)255;
    return r;
}

extern "C" void kernel_launch(void* const* d_in, const int* in_sizes, int n_in,
                              void* d_out, int out_size, void* d_ws, size_t ws_size,
                              hipStream_t stream)
{
    const int* edge_index = (const int*)d_in[0];
    int E = in_sizes[0] / 2;
    int N = in_sizes[2] / 128;
    const int* srcv = edge_index;
    const int* dstv = edge_index + E;
    const float* eattr = (const float*)d_in[1];
    const float* x = (const float*)d_in[2];

    char* p = (char*)d_ws;
    int*   deg    = (int*)  carve(p, (size_t)N * 4);
    int*   fill   = (int*)  carve(p, (size_t)N * 4);
    int*   rowptr = (int*)  carve(p, (size_t)(N + 1) * 4);
    int*   bsum   = (int*)  carve(p, (size_t)1024 * 4);
    int*   col    = (int*)  carve(p, (size_t)(E + N) * 4);
    float* eperm  = (float*)carve(p, (size_t)(E + N) * 16);
    unsigned short* xlh = (unsigned short*)carve(p, (size_t)N * 256);
    unsigned short* xrh = (unsigned short*)carve(p, (size_t)N * 256);
    unsigned short* Thi = (unsigned short*)carve(p, (size_t)3 * 256 * 128 * 2);
    unsigned short* Tlo = (unsigned short*)carve(p, (size_t)3 * 256 * 128 * 2);

    hipMemsetAsync(deg,  0, (size_t)N * 4, stream);
    hipMemsetAsync(fill, 0, (size_t)N * 4, stream);

    int NB = (N + 1023) / 1024;
    count_deg_kernel<<<(E + 255) / 256, 256, 0, stream>>>(dstv, deg, E);
    scanA_kernel<<<NB, 256, 0, stream>>>(deg, bsum, N);
    scanB_kernel<<<1, 1024, 0, stream>>>(bsum, NB);
    scanC_kernel<<<NB, 256, 0, stream>>>(deg, bsum, rowptr, N);
    fill_csr_kernel<<<(E + 255) / 256, 256, 0, stream>>>(srcv, dstv, eattr, rowptr, fill, col, eperm, E);
    selfloop_kernel<<<(N + 255) / 256, 256, 0, stream>>>(rowptr, deg, col, eperm, N);

    for (int li = 0; li < 3; ++li) {
        const float* Wl = (const float*)d_in[3 + 5 * li + 0];
        const float* Wr = (const float*)d_in[3 + 5 * li + 1];
        wprep_kernel<<<256, 128, 0, stream>>>(Wl, Wr,
                                              Thi + (size_t)li * 256 * 128,
                                              Tlo + (size_t)li * 256 * 128);
    }

    float* out = (float*)d_out;
    for (int li = 0; li < 3; ++li) {
        const float* Wep = (const float*)d_in[3 + 5 * li + 2];
        const float* atp = (const float*)d_in[3 + 5 * li + 3];
        const float* bp  = (const float*)d_in[3 + 5 * li + 4];
        const float* hin = (li == 0) ? x : out;
        gemm_mfma_kernel<<<(N + 31) / 32, 256, 0, stream>>>(
            hin, Thi + (size_t)li * 256 * 128, Tlo + (size_t)li * 256 * 128, xlh, xrh, N);
        gat_agg_kernel<<<(N + 15) / 16, 256, 0, stream>>>(xlh, xrh, rowptr, col, eperm,
                                                          Wep, atp, bp, out, N, li < 2 ? 1 : 0);
    }
}

// Round 8
// 743.539 us; speedup vs baseline: 1.1876x; 1.1876x over previous
//
#include <hip/hip_runtime.h>
#include <hip/hip_bf16.h>
#include <cmath>

#define SLOPE 0.2f

typedef __attribute__((ext_vector_type(8))) short bf16x8;
typedef __attribute__((ext_vector_type(4))) float f32x4;
typedef __attribute__((ext_vector_type(2))) float f32x2;

union bfpack { bf16x8 v; unsigned int u[4]; };

__device__ __forceinline__ unsigned short bf16_rne(float x) {
    unsigned int b = __float_as_uint(x);
    b += 0x7FFFu + ((b >> 16) & 1u);
    return (unsigned short)(b >> 16);
}
__device__ __forceinline__ float bf16_tof(unsigned short h) {
    return __uint_as_float(((unsigned int)h) << 16);
}
__device__ __forceinline__ f32x2 splat2(float s) { return (f32x2){s, s}; }

// sum over 16-lane groups entirely in the VALU via DPP (no ds_bpermute):
// xor1 (quad_perm 0xB1), xor2 (quad_perm 0x4E), xor7 (row_half_mirror 0x141,
// quads already uniform so bit2 flip is all that matters), xor15 (row_mirror
// 0x140, flips bit3 across the 16-lane row).
__device__ __forceinline__ float dpp_red16(float x) {
    int y;
    y = __builtin_amdgcn_update_dpp(0, __float_as_int(x), 0xB1, 0xF, 0xF, true);
    x += __int_as_float(y);
    y = __builtin_amdgcn_update_dpp(0, __float_as_int(x), 0x4E, 0xF, 0xF, true);
    x += __int_as_float(y);
    y = __builtin_amdgcn_update_dpp(0, __float_as_int(x), 0x141, 0xF, 0xF, true);
    x += __int_as_float(y);
    y = __builtin_amdgcn_update_dpp(0, __float_as_int(x), 0x140, 0xF, 0xF, true);
    x += __int_as_float(y);
    return x;
}

// ---------------------------------------------------------------- preprocessing

__global__ __launch_bounds__(256) void count_deg_kernel(
    const int* __restrict__ dstv, int* __restrict__ deg, int E)
{
    int e = blockIdx.x * 256 + threadIdx.x;
    if (e >= E) return;
    atomicAdd(&deg[dstv[e]], 1);
}

// multi-block exclusive scan over (deg[i]+1), 1024 elems per block
__global__ __launch_bounds__(256) void scanA_kernel(
    const int* __restrict__ deg, int* __restrict__ bsum, int N)
{
    __shared__ int wsum[4];
    int t = threadIdx.x;
    int base = blockIdx.x * 1024 + t * 4;
    int s = 0;
    #pragma unroll
    for (int j = 0; j < 4; ++j) {
        int i = base + j;
        if (i < N) s += deg[i] + 1;
    }
    #pragma unroll
    for (int off = 1; off < 64; off <<= 1) s += __shfl_xor(s, off);
    if ((t & 63) == 0) wsum[t >> 6] = s;
    __syncthreads();
    if (t == 0) bsum[blockIdx.x] = wsum[0] + wsum[1] + wsum[2] + wsum[3];
}

// inclusive scan of nb (<=1024) block sums, in place
__global__ void scanB_kernel(int* __restrict__ bsum, int nb)
{
    __shared__ int wsum[16];
    int t = threadIdx.x, lane = t & 63, w = t >> 6;
    int v = (t < nb) ? bsum[t] : 0;
    #pragma unroll
    for (int off = 1; off < 64; off <<= 1) {
        int u = __shfl_up(v, off);
        if (lane >= off) v += u;
    }
    if (lane == 63) wsum[w] = v;
    __syncthreads();
    int add = 0;
    for (int i = 0; i < w; ++i) add += wsum[i];
    v += add;
    if (t < nb) bsum[t] = v;
}

__global__ __launch_bounds__(256) void scanC_kernel(
    const int* __restrict__ deg, const int* __restrict__ bsum,
    int* __restrict__ rowptr, int N)
{
    __shared__ int wsum[4];
    int t = threadIdx.x, lane = t & 63, w = t >> 6;
    int base = blockIdx.x * 1024 + t * 4;
    int v[4];
    int s = 0;
    #pragma unroll
    for (int j = 0; j < 4; ++j) {
        int i = base + j;
        v[j] = (i < N) ? (deg[i] + 1) : 0;
        s += v[j];
    }
    int incl = s;
    #pragma unroll
    for (int off = 1; off < 64; off <<= 1) {
        int u = __shfl_up(incl, off);
        if (lane >= off) incl += u;
    }
    if (lane == 63) wsum[w] = incl;
    __syncthreads();
    int wadd = 0;
    for (int i = 0; i < w; ++i) wadd += wsum[i];
    int boff = blockIdx.x ? bsum[blockIdx.x - 1] : 0;
    int running = boff + wadd + (incl - s);
    #pragma unroll
    for (int j = 0; j < 4; ++j) {
        int i = base + j;
        running += v[j];
        if (i < N) rowptr[i + 1] = running;
    }
    if (blockIdx.x == 0 && t == 0) rowptr[0] = 0;
}

__global__ __launch_bounds__(256) void fill_csr_kernel(
    const int* __restrict__ srcv, const int* __restrict__ dstv,
    const float* __restrict__ eattr,
    const int* __restrict__ rowptr, int* __restrict__ fill,
    int* __restrict__ col, float* __restrict__ eattr_perm, int E)
{
    int e = blockIdx.x * 256 + threadIdx.x;
    if (e >= E) return;
    int d = dstv[e];
    int pos = rowptr[d] + atomicAdd(&fill[d], 1);
    col[pos] = srcv[e];
    *(float4*)&eattr_perm[(size_t)pos * 4] = *(const float4*)&eattr[(size_t)e * 4];
}

__global__ __launch_bounds__(256) void selfloop_kernel(
    const int* __restrict__ rowptr, const int* __restrict__ deg,
    int* __restrict__ col, float* __restrict__ eattr_perm, int N)
{
    int n = blockIdx.x * 256 + threadIdx.x;
    if (n >= N) return;
    int e0 = rowptr[n], e1 = rowptr[n + 1];
    float4 s = make_float4(0.f, 0.f, 0.f, 0.f);
    for (int e = e0; e < e1 - 1; ++e) {
        float4 a = *(const float4*)&eattr_perm[(size_t)e * 4];
        s.x += a.x; s.y += a.y; s.z += a.z; s.w += a.w;
    }
    float inv = 1.0f / fmaxf((float)deg[n], 1.0f);
    s.x *= inv; s.y *= inv; s.z *= inv; s.w *= inv;
    int pos = e1 - 1;
    col[pos] = n;
    *(float4*)&eattr_perm[(size_t)pos * 4] = s;
}

// W prep: Thi/Tlo[c][k] = bf16 hi/lo split of W[k][c], c in [0,256) = Wl|Wr.
__global__ __launch_bounds__(128) void wprep_kernel(
    const float* __restrict__ Wl, const float* __restrict__ Wr,
    unsigned short* __restrict__ Thi, unsigned short* __restrict__ Tlo)
{
    int c = blockIdx.x;      // 0..255
    int k = threadIdx.x;     // 0..127
    const float* W = (c < 128) ? Wl : Wr;
    float v = W[(size_t)k * 128 + (c & 127)];
    unsigned short h = bf16_rne(v);
    float lo = v - bf16_tof(h);
    Thi[(size_t)c * 128 + k] = h;
    Tlo[(size_t)c * 128 + k] = bf16_rne(lo);
}

// ---------------------------------------------------------------- MFMA GEMM (bf16x3)
// XLH|XRH (both bf16) = H @ [Wl|Wr].  32-row tile, 4 waves (64-col quadrant each).
__global__ __launch_bounds__(256, 4) void gemm_mfma_kernel(
    const float* __restrict__ H,
    const unsigned short* __restrict__ Thi, const unsigned short* __restrict__ Tlo,
    unsigned short* __restrict__ XLH, unsigned short* __restrict__ XRH, int nrows)
{
    __shared__ unsigned short sHi[32 * 128];
    __shared__ unsigned short sLo[32 * 128];
    int t = threadIdx.x;
    int r0 = blockIdx.x * 32;

    #pragma unroll
    for (int i = 0; i < 2; ++i) {
        int idx = t + i * 256;           // 512 = 32 rows * 16 chunks
        int row = idx >> 4, chunk = idx & 15;
        int gr = min(r0 + row, nrows - 1);
        float4 a = *(const float4*)&H[(size_t)gr * 128 + chunk * 8];
        float4 b = *(const float4*)&H[(size_t)gr * 128 + chunk * 8 + 4];
        float v[8] = {a.x, a.y, a.z, a.w, b.x, b.y, b.z, b.w};
        union { bf16x8 v; unsigned short u[8]; } hv, lv;
        #pragma unroll
        for (int j = 0; j < 8; ++j) {
            unsigned short h = bf16_rne(v[j]);
            hv.u[j] = h;
            lv.u[j] = bf16_rne(v[j] - bf16_tof(h));
        }
        int slot = chunk ^ (row & 7);
        *(bf16x8*)&sHi[row * 128 + slot * 8] = hv.v;
        *(bf16x8*)&sLo[row * 128 + slot * 8] = lv.v;
    }
    __syncthreads();

    int w  = t >> 6;
    int l  = t & 63;
    int lr = l & 15;
    int lk = l >> 4;
    int cbase = w * 64;

    f32x4 acc[2][4];
    #pragma unroll
    for (int i = 0; i < 2; ++i)
        #pragma unroll
        for (int j = 0; j < 4; ++j)
            acc[i][j] = (f32x4){0.f, 0.f, 0.f, 0.f};

    #pragma unroll
    for (int k0 = 0; k0 < 128; k0 += 32) {
        bf16x8 ah[2], al[2];
        #pragma unroll
        for (int rt = 0; rt < 2; ++rt) {
            int row = rt * 16 + lr;
            int chunk = (k0 >> 3) + lk;
            int slot = chunk ^ (row & 7);
            ah[rt] = *(const bf16x8*)&sHi[row * 128 + slot * 8];
            al[rt] = *(const bf16x8*)&sLo[row * 128 + slot * 8];
        }
        int k = k0 + lk * 8;
        #pragma unroll
        for (int ct = 0; ct < 4; ++ct) {
            int c = cbase + ct * 16 + lr;
            bf16x8 bh = *(const bf16x8*)&Thi[(size_t)c * 128 + k];
            bf16x8 bl = *(const bf16x8*)&Tlo[(size_t)c * 128 + k];
            #pragma unroll
            for (int rt = 0; rt < 2; ++rt) {
                acc[rt][ct] = __builtin_amdgcn_mfma_f32_16x16x32_bf16(ah[rt], bh, acc[rt][ct], 0, 0, 0);
                acc[rt][ct] = __builtin_amdgcn_mfma_f32_16x16x32_bf16(al[rt], bh, acc[rt][ct], 0, 0, 0);
                acc[rt][ct] = __builtin_amdgcn_mfma_f32_16x16x32_bf16(ah[rt], bl, acc[rt][ct], 0, 0, 0);
            }
        }
    }

    unsigned short* OUT = (w < 2) ? XLH : XRH;
    int ccol0 = (cbase & 127);
    #pragma unroll
    for (int rt = 0; rt < 2; ++rt)
        #pragma unroll
        for (int ct = 0; ct < 4; ++ct) {
            int cc = ccol0 + ct * 16 + lr;
            #pragma unroll
            for (int q = 0; q < 4; ++q) {
                int r = r0 + rt * 16 + lk * 4 + q;
                if (r < nrows) OUT[(size_t)r * 128 + cc] = bf16_rne(acc[rt][ct][q]);
            }
        }
}

// ---------------------------------------------------------------- fused GATv2 attention + aggregation
// wave = 4 consecutive nodes; 4 edges in flight (16 lanes/edge, 8 ch/lane);
// packed-f32 math, DPP in-group score reduce, defer-max softmax, 1-deep prefetch.
__global__ __launch_bounds__(256) void gat_agg_kernel(
    const unsigned short* __restrict__ xlh, const unsigned short* __restrict__ xrh,
    const int* __restrict__ rowptr, const int* __restrict__ col,
    const float* __restrict__ eattr_perm,
    const float* __restrict__ We, const float* __restrict__ att, const float* __restrict__ bias,
    float* __restrict__ out, int N, int do_relu)
{
    int w = threadIdx.x >> 6;
    int lane = threadIdx.x & 63;
    int g = lane >> 4;
    int lg = lane & 15;
    int c0 = lg * 8;

    f32x2 at2[4], we2[4][4];
    float bv[8];
    #pragma unroll
    for (int p = 0; p < 4; ++p) at2[p] = (f32x2){att[c0 + 2 * p], att[c0 + 2 * p + 1]};
    #pragma unroll
    for (int j = 0; j < 8; ++j) bv[j] = bias[c0 + j];
    #pragma unroll
    for (int k = 0; k < 4; ++k)
        #pragma unroll
        for (int p = 0; p < 4; ++p)
            we2[k][p] = (f32x2){We[k * 128 + c0 + 2 * p], We[k * 128 + c0 + 2 * p + 1]};

    int nbase = (blockIdx.x * 4 + w) * 4;
    for (int i = 0; i < 4; ++i) {
        int n = nbase + i;
        if (n >= N) return;           // wave-uniform

        f32x2 xr2[4];
        {
            bfpack xrp;
            xrp.v = *(const bf16x8*)&xrh[((size_t)n << 7) + c0];
            #pragma unroll
            for (int p = 0; p < 4; ++p) {
                unsigned int u = xrp.u[p];
                xr2[p] = (f32x2){__uint_as_float(u << 16), __uint_as_float(u & 0xffff0000u)};
            }
        }

        int e0 = rowptr[n], e1 = rowptr[n + 1];
        float m = -INFINITY, den = 0.f;
        f32x2 acc2[4];
        #pragma unroll
        for (int p = 0; p < 4; ++p) acc2[p] = (f32x2){0.f, 0.f};

        int e = e0 + g;
        // prefetch first edge
        float4 eavN = make_float4(0.f, 0.f, 0.f, 0.f);
        bfpack xvN;
        xvN.u[0] = xvN.u[1] = xvN.u[2] = xvN.u[3] = 0;
        if (e < e1) {
            int s = col[e];
            eavN = *(const float4*)&eattr_perm[(size_t)e * 4];
            xvN.v = *(const bf16x8*)&xlh[((size_t)(unsigned)s << 7) + c0];
        }

        while (e < e1) {
            float4 eav = eavN;
            bfpack xv = xvN;
            int en = e + 4;
            if (en < e1) {
                int s2 = col[en];
                eavN = *(const float4*)&eattr_perm[(size_t)en * 4];
                xvN.v = *(const bf16x8*)&xlh[((size_t)(unsigned)s2 << 7) + c0];
            }

            // decode bf16 pairs -> f32x2 (lo = bits<<16, hi = bits&0xffff0000)
            f32x2 xl2[4];
            #pragma unroll
            for (int p = 0; p < 4; ++p) {
                unsigned int u = xv.u[p];
                xl2[p] = (f32x2){__uint_as_float(u << 16), __uint_as_float(u & 0xffff0000u)};
            }
            f32x2 vd = (f32x2){0.f, 0.f};
            #pragma unroll
            for (int p = 0; p < 4; ++p) {
                f32x2 z = xl2[p] + xr2[p];
                z += splat2(eav.x) * we2[0][p];
                z += splat2(eav.y) * we2[1][p];
                z += splat2(eav.z) * we2[2][p];
                z += splat2(eav.w) * we2[3][p];
                f32x2 zs = splat2(SLOPE) * z;
                f32x2 lz = (f32x2){fmaxf(z.x, zs.x), fmaxf(z.y, zs.y)};
                vd += lz * at2[p];
            }
            float v = dpp_red16(vd.x + vd.y);   // VALU-only 16-lane sum

            if (v - m > 8.0f) {          // rare: new max grew past threshold
                float scale = __expf(m - v);     // 0 on first edge (m=-inf)
                den = den * scale + 1.0f;
                #pragma unroll
                for (int p = 0; p < 4; ++p) acc2[p] = acc2[p] * splat2(scale) + xl2[p];
                m = v;
            } else {                     // common: no rescale (P bounded by e^8)
                float wgt = __expf(v - m);
                den += wgt;
                #pragma unroll
                for (int p = 0; p < 4; ++p) acc2[p] += splat2(wgt) * xl2[p];
            }
            e = en;
        }

        // combine 4 groups (differing running maxima)
        float M = fmaxf(m, __shfl_xor(m, 16));
        M = fmaxf(M, __shfl_xor(M, 32));
        float sc = __expf(m - M);        // 0 for empty groups
        float d2 = den * sc;
        d2 += __shfl_xor(d2, 16);
        d2 += __shfl_xor(d2, 32);
        float inv = 1.f / (d2 + 1e-16f);
        float o[8];
        #pragma unroll
        for (int p = 0; p < 4; ++p) {
            float ax = acc2[p].x * sc;
            float ay = acc2[p].y * sc;
            ax += __shfl_xor(ax, 16); ax += __shfl_xor(ax, 32);
            ay += __shfl_xor(ay, 16); ay += __shfl_xor(ay, 32);
            float vx = ax * inv + bv[2 * p];
            float vy = ay * inv + bv[2 * p + 1];
            o[2 * p]     = do_relu ? fmaxf(vx, 0.f) : vx;
            o[2 * p + 1] = do_relu ? fmaxf(vy, 0.f) : vy;
        }
        if (g == 0) {
            *(float4*)&out[((size_t)n << 7) + c0]     = make_float4(o[0], o[1], o[2], o[3]);
            *(float4*)&out[((size_t)n << 7) + c0 + 4] = make_float4(o[4], o[5], o[6], o[7]);
        }
    }
}

// ---------------------------------------------------------------- launch

static inline char* carve(char*& p, size_t bytes) {
    char* r = p;
    p += (bytes + 255) & ~(size_t)255;
    return r;
}

extern "C" void kernel_launch(void* const* d_in, const int* in_sizes, int n_in,
                              void* d_out, int out_size, void* d_ws, size_t ws_size,
                              hipStream_t stream)
{
    const int* edge_index = (const int*)d_in[0];
    int E = in_sizes[0] / 2;
    int N = in_sizes[2] / 128;
    const int* srcv = edge_index;
    const int* dstv = edge_index + E;
    const float* eattr = (const float*)d_in[1];
    const float* x = (const float*)d_in[2];

    char* p = (char*)d_ws;
    int*   deg    = (int*)  carve(p, (size_t)N * 4);
    int*   fill   = (int*)  carve(p, (size_t)N * 4);
    int*   rowptr = (int*)  carve(p, (size_t)(N + 1) * 4);
    int*   bsum   = (int*)  carve(p, (size_t)1024 * 4);
    int*   col    = (int*)  carve(p, (size_t)(E + N) * 4);
    float* eperm  = (float*)carve(p, (size_t)(E + N) * 16);
    unsigned short* xlh = (unsigned short*)carve(p, (size_t)N * 256);
    unsigned short* xrh = (unsigned short*)carve(p, (size_t)N * 256);
    unsigned short* Thi = (unsigned short*)carve(p, (size_t)3 * 256 * 128 * 2);
    unsigned short* Tlo = (unsigned short*)carve(p, (size_t)3 * 256 * 128 * 2);

    hipMemsetAsync(deg,  0, (size_t)N * 4, stream);
    hipMemsetAsync(fill, 0, (size_t)N * 4, stream);

    int NB = (N + 1023) / 1024;
    count_deg_kernel<<<(E + 255) / 256, 256, 0, stream>>>(dstv, deg, E);
    scanA_kernel<<<NB, 256, 0, stream>>>(deg, bsum, N);
    scanB_kernel<<<1, 1024, 0, stream>>>(bsum, NB);
    scanC_kernel<<<NB, 256, 0, stream>>>(deg, bsum, rowptr, N);
    fill_csr_kernel<<<(E + 255) / 256, 256, 0, stream>>>(srcv, dstv, eattr, rowptr, fill, col, eperm, E);
    selfloop_kernel<<<(N + 255) / 256, 256, 0, stream>>>(rowptr, deg, col, eperm, N);

    for (int li = 0; li < 3; ++li) {
        const float* Wl = (const float*)d_in[3 + 5 * li + 0];
        const float* Wr = (const float*)d_in[3 + 5 * li + 1];
        wprep_kernel<<<256, 128, 0, stream>>>(Wl, Wr,
                                              Thi + (size_t)li * 256 * 128,
                                              Tlo + (size_t)li * 256 * 128);
    }

    float* out = (float*)d_out;
    for (int li = 0; li < 3; ++li) {
        const float* Wep = (const float*)d_in[3 + 5 * li + 2];
        const float* atp = (const float*)d_in[3 + 5 * li + 3];
        const float* bp  = (const float*)d_in[3 + 5 * li + 4];
        const float* hin = (li == 0) ? x : out;
        gemm_mfma_kernel<<<(N + 31) / 32, 256, 0, stream>>>(
            hin, Thi + (size_t)li * 256 * 128, Tlo + (size_t)li * 256 * 128, xlh, xrh, N);
        gat_agg_kernel<<<(N + 15) / 16, 256, 0, stream>>>(xlh, xrh, rowptr, col, eperm,
                                                          Wep, atp, bp, out, N, li < 2 ? 1 : 0);
    }
}

// Round 9
// 685.181 us; speedup vs baseline: 1.2888x; 1.0852x over previous
//
#include <hip/hip_runtime.h>
#include <hip/hip_bf16.h>
#include <cmath>

#define SLOPE 0.2f

typedef __attribute__((ext_vector_type(8))) short bf16x8;
typedef __attribute__((ext_vector_type(4))) float f32x4;
typedef __attribute__((ext_vector_type(2))) float f32x2;

union bfpack { bf16x8 v; unsigned int u[4]; };

__device__ __forceinline__ unsigned short bf16_rne(float x) {
    unsigned int b = __float_as_uint(x);
    b += 0x7FFFu + ((b >> 16) & 1u);
    return (unsigned short)(b >> 16);
}
__device__ __forceinline__ float bf16_tof(unsigned short h) {
    return __uint_as_float(((unsigned int)h) << 16);
}
__device__ __forceinline__ f32x2 splat2(float s) { return (f32x2){s, s}; }

// sum over 16-lane groups entirely in the VALU via DPP (no ds_bpermute):
// xor1 (quad_perm 0xB1), xor2 (quad_perm 0x4E), xor7 (row_half_mirror 0x141,
// quads already uniform), xor15 (row_mirror 0x140).
__device__ __forceinline__ float dpp_red16(float x) {
    int y;
    y = __builtin_amdgcn_update_dpp(0, __float_as_int(x), 0xB1, 0xF, 0xF, true);
    x += __int_as_float(y);
    y = __builtin_amdgcn_update_dpp(0, __float_as_int(x), 0x4E, 0xF, 0xF, true);
    x += __int_as_float(y);
    y = __builtin_amdgcn_update_dpp(0, __float_as_int(x), 0x141, 0xF, 0xF, true);
    x += __int_as_float(y);
    y = __builtin_amdgcn_update_dpp(0, __float_as_int(x), 0x140, 0xF, 0xF, true);
    x += __int_as_float(y);
    return x;
}

// ---------------------------------------------------------------- preprocessing

__global__ __launch_bounds__(256) void count_deg_kernel(
    const int* __restrict__ dstv, int* __restrict__ deg, int E)
{
    int e = blockIdx.x * 256 + threadIdx.x;
    if (e >= E) return;
    atomicAdd(&deg[dstv[e]], 1);
}

// multi-block exclusive scan over (deg[i]+1), 1024 elems per block
__global__ __launch_bounds__(256) void scanA_kernel(
    const int* __restrict__ deg, int* __restrict__ bsum, int N)
{
    __shared__ int wsum[4];
    int t = threadIdx.x;
    int base = blockIdx.x * 1024 + t * 4;
    int s = 0;
    #pragma unroll
    for (int j = 0; j < 4; ++j) {
        int i = base + j;
        if (i < N) s += deg[i] + 1;
    }
    #pragma unroll
    for (int off = 1; off < 64; off <<= 1) s += __shfl_xor(s, off);
    if ((t & 63) == 0) wsum[t >> 6] = s;
    __syncthreads();
    if (t == 0) bsum[blockIdx.x] = wsum[0] + wsum[1] + wsum[2] + wsum[3];
}

// inclusive scan of nb (<=1024) block sums, in place
__global__ void scanB_kernel(int* __restrict__ bsum, int nb)
{
    __shared__ int wsum[16];
    int t = threadIdx.x, lane = t & 63, w = t >> 6;
    int v = (t < nb) ? bsum[t] : 0;
    #pragma unroll
    for (int off = 1; off < 64; off <<= 1) {
        int u = __shfl_up(v, off);
        if (lane >= off) v += u;
    }
    if (lane == 63) wsum[w] = v;
    __syncthreads();
    int add = 0;
    for (int i = 0; i < w; ++i) add += wsum[i];
    v += add;
    if (t < nb) bsum[t] = v;
}

__global__ __launch_bounds__(256) void scanC_kernel(
    const int* __restrict__ deg, const int* __restrict__ bsum,
    int* __restrict__ rowptr, int N)
{
    __shared__ int wsum[4];
    int t = threadIdx.x, lane = t & 63, w = t >> 6;
    int base = blockIdx.x * 1024 + t * 4;
    int v[4];
    int s = 0;
    #pragma unroll
    for (int j = 0; j < 4; ++j) {
        int i = base + j;
        v[j] = (i < N) ? (deg[i] + 1) : 0;
        s += v[j];
    }
    int incl = s;
    #pragma unroll
    for (int off = 1; off < 64; off <<= 1) {
        int u = __shfl_up(incl, off);
        if (lane >= off) incl += u;
    }
    if (lane == 63) wsum[w] = incl;
    __syncthreads();
    int wadd = 0;
    for (int i = 0; i < w; ++i) wadd += wsum[i];
    int boff = blockIdx.x ? bsum[blockIdx.x - 1] : 0;
    int running = boff + wadd + (incl - s);
    #pragma unroll
    for (int j = 0; j < 4; ++j) {
        int i = base + j;
        running += v[j];
        if (i < N) rowptr[i + 1] = running;
    }
    if (blockIdx.x == 0 && t == 0) rowptr[0] = 0;
}

__global__ __launch_bounds__(256) void fill_csr_kernel(
    const int* __restrict__ srcv, const int* __restrict__ dstv,
    const float* __restrict__ eattr,
    const int* __restrict__ rowptr, int* __restrict__ fill,
    int* __restrict__ col, float* __restrict__ eattr_perm, int E)
{
    int e = blockIdx.x * 256 + threadIdx.x;
    if (e >= E) return;
    int d = dstv[e];
    int pos = rowptr[d] + atomicAdd(&fill[d], 1);
    col[pos] = srcv[e];
    *(float4*)&eattr_perm[(size_t)pos * 4] = *(const float4*)&eattr[(size_t)e * 4];
}

__global__ __launch_bounds__(256) void selfloop_kernel(
    const int* __restrict__ rowptr, const int* __restrict__ deg,
    int* __restrict__ col, float* __restrict__ eattr_perm, int N)
{
    int n = blockIdx.x * 256 + threadIdx.x;
    if (n >= N) return;
    int e0 = rowptr[n], e1 = rowptr[n + 1];
    float4 s = make_float4(0.f, 0.f, 0.f, 0.f);
    for (int e = e0; e < e1 - 1; ++e) {
        float4 a = *(const float4*)&eattr_perm[(size_t)e * 4];
        s.x += a.x; s.y += a.y; s.z += a.z; s.w += a.w;
    }
    float inv = 1.0f / fmaxf((float)deg[n], 1.0f);
    s.x *= inv; s.y *= inv; s.z *= inv; s.w *= inv;
    int pos = e1 - 1;
    col[pos] = n;
    *(float4*)&eattr_perm[(size_t)pos * 4] = s;
}

// W prep: Thi/Tlo[c][k] = bf16 hi/lo split of W[k][c], c in [0,256) = Wl|Wr.
__global__ __launch_bounds__(128) void wprep_kernel(
    const float* __restrict__ Wl, const float* __restrict__ Wr,
    unsigned short* __restrict__ Thi, unsigned short* __restrict__ Tlo)
{
    int c = blockIdx.x;      // 0..255
    int k = threadIdx.x;     // 0..127
    const float* W = (c < 128) ? Wl : Wr;
    float v = W[(size_t)k * 128 + (c & 127)];
    unsigned short h = bf16_rne(v);
    float lo = v - bf16_tof(h);
    Thi[(size_t)c * 128 + k] = h;
    Tlo[(size_t)c * 128 + k] = bf16_rne(lo);
}

// ---------------------------------------------------------------- MFMA GEMM (bf16x3)
// XLH|XRH (both bf16) = H @ [Wl|Wr].  32-row tile, 4 waves (64-col quadrant each).
__global__ __launch_bounds__(256, 4) void gemm_mfma_kernel(
    const float* __restrict__ H,
    const unsigned short* __restrict__ Thi, const unsigned short* __restrict__ Tlo,
    unsigned short* __restrict__ XLH, unsigned short* __restrict__ XRH, int nrows)
{
    __shared__ unsigned short sHi[32 * 128];
    __shared__ unsigned short sLo[32 * 128];
    int t = threadIdx.x;
    int r0 = blockIdx.x * 32;

    #pragma unroll
    for (int i = 0; i < 2; ++i) {
        int idx = t + i * 256;           // 512 = 32 rows * 16 chunks
        int row = idx >> 4, chunk = idx & 15;
        int gr = min(r0 + row, nrows - 1);
        float4 a = *(const float4*)&H[(size_t)gr * 128 + chunk * 8];
        float4 b = *(const float4*)&H[(size_t)gr * 128 + chunk * 8 + 4];
        float v[8] = {a.x, a.y, a.z, a.w, b.x, b.y, b.z, b.w};
        union { bf16x8 v; unsigned short u[8]; } hv, lv;
        #pragma unroll
        for (int j = 0; j < 8; ++j) {
            unsigned short h = bf16_rne(v[j]);
            hv.u[j] = h;
            lv.u[j] = bf16_rne(v[j] - bf16_tof(h));
        }
        int slot = chunk ^ (row & 7);
        *(bf16x8*)&sHi[row * 128 + slot * 8] = hv.v;
        *(bf16x8*)&sLo[row * 128 + slot * 8] = lv.v;
    }
    __syncthreads();

    int w  = t >> 6;
    int l  = t & 63;
    int lr = l & 15;
    int lk = l >> 4;
    int cbase = w * 64;

    f32x4 acc[2][4];
    #pragma unroll
    for (int i = 0; i < 2; ++i)
        #pragma unroll
        for (int j = 0; j < 4; ++j)
            acc[i][j] = (f32x4){0.f, 0.f, 0.f, 0.f};

    #pragma unroll
    for (int k0 = 0; k0 < 128; k0 += 32) {
        bf16x8 ah[2], al[2];
        #pragma unroll
        for (int rt = 0; rt < 2; ++rt) {
            int row = rt * 16 + lr;
            int chunk = (k0 >> 3) + lk;
            int slot = chunk ^ (row & 7);
            ah[rt] = *(const bf16x8*)&sHi[row * 128 + slot * 8];
            al[rt] = *(const bf16x8*)&sLo[row * 128 + slot * 8];
        }
        int k = k0 + lk * 8;
        #pragma unroll
        for (int ct = 0; ct < 4; ++ct) {
            int c = cbase + ct * 16 + lr;
            bf16x8 bh = *(const bf16x8*)&Thi[(size_t)c * 128 + k];
            bf16x8 bl = *(const bf16x8*)&Tlo[(size_t)c * 128 + k];
            #pragma unroll
            for (int rt = 0; rt < 2; ++rt) {
                acc[rt][ct] = __builtin_amdgcn_mfma_f32_16x16x32_bf16(ah[rt], bh, acc[rt][ct], 0, 0, 0);
                acc[rt][ct] = __builtin_amdgcn_mfma_f32_16x16x32_bf16(al[rt], bh, acc[rt][ct], 0, 0, 0);
                acc[rt][ct] = __builtin_amdgcn_mfma_f32_16x16x32_bf16(ah[rt], bl, acc[rt][ct], 0, 0, 0);
            }
        }
    }

    unsigned short* OUT = (w < 2) ? XLH : XRH;
    int ccol0 = (cbase & 127);
    #pragma unroll
    for (int rt = 0; rt < 2; ++rt)
        #pragma unroll
        for (int ct = 0; ct < 4; ++ct) {
            int cc = ccol0 + ct * 16 + lr;
            #pragma unroll
            for (int q = 0; q < 4; ++q) {
                int r = r0 + rt * 16 + lk * 4 + q;
                if (r < nrows) OUT[(size_t)r * 128 + cc] = bf16_rne(acc[rt][ct][q]);
            }
        }
}

// ---------------------------------------------------------------- fused GATv2 attention + aggregation
// wave = 4 consecutive nodes; 4 edges in flight (16 lanes/edge, 8 ch/lane);
// packed-f32 math, DPP reduce, wave-uniform defer-max, decoupled col pipeline
// (index loaded a full iteration before its use as the gather address).
__global__ __launch_bounds__(256) void gat_agg_kernel(
    const unsigned short* __restrict__ xlh, const unsigned short* __restrict__ xrh,
    const int* __restrict__ rowptr, const int* __restrict__ col,
    const float* __restrict__ eattr_perm,
    const float* __restrict__ We, const float* __restrict__ att, const float* __restrict__ bias,
    float* __restrict__ out, int N, int do_relu)
{
    int w = threadIdx.x >> 6;
    int lane = threadIdx.x & 63;
    int g = lane >> 4;
    int lg = lane & 15;
    int c0 = lg * 8;

    f32x2 at2[4], we2[4][4];
    float bv[8];
    #pragma unroll
    for (int p = 0; p < 4; ++p) at2[p] = (f32x2){att[c0 + 2 * p], att[c0 + 2 * p + 1]};
    #pragma unroll
    for (int j = 0; j < 8; ++j) bv[j] = bias[c0 + j];
    #pragma unroll
    for (int k = 0; k < 4; ++k)
        #pragma unroll
        for (int p = 0; p < 4; ++p)
            we2[k][p] = (f32x2){We[k * 128 + c0 + 2 * p], We[k * 128 + c0 + 2 * p + 1]};

    int nbase = (blockIdx.x * 4 + w) * 4;
    if (nbase >= N) return;

    // rowptr[nbase..nbase+4] once per wave (clamped; rowptr[N] is valid)
    int rptr[5];
    #pragma unroll
    for (int j = 0; j < 5; ++j) rptr[j] = rowptr[min(nbase + j, N)];

    #pragma unroll 1
    for (int i = 0; i < 4; ++i) {
        int n = nbase + i;
        int nc = min(n, N - 1);

        f32x2 xr2[4];
        {
            bfpack xrp;
            xrp.v = *(const bf16x8*)&xrh[((size_t)nc << 7) + c0];
            #pragma unroll
            for (int p = 0; p < 4; ++p) {
                unsigned int u = xrp.u[p];
                xr2[p] = (f32x2){__uint_as_float(u << 16), __uint_as_float(u & 0xffff0000u)};
            }
        }

        int e0 = rptr[i], e1 = rptr[i + 1];
        float m = -INFINITY, den = 0.f;
        f32x2 acc2[4];
        #pragma unroll
        for (int p = 0; p < 4; ++p) acc2[p] = (f32x2){0.f, 0.f};

        int e = e0 + g;
        float4 ea0 = make_float4(0.f, 0.f, 0.f, 0.f);
        bfpack xl0;
        xl0.u[0] = xl0.u[1] = xl0.u[2] = xl0.u[3] = 0;
        int cA = 0;
        if (e < e1) {
            int cc = col[e];
            if (e + 4 < e1) cA = col[e + 4];     // issue both index loads together
            ea0 = *(const float4*)&eattr_perm[(size_t)e * 4];
            xl0.v = *(const bf16x8*)&xlh[((size_t)(unsigned)cc << 7) + c0];
        }

        while (e < e1) {
            int en = e + 4;
            bool hn = (en < e1);
            float4 ea1;
            bfpack xl1;
            if (hn) {
                // cA was loaded >= 1 iteration ago: no index-wait on this path
                ea1 = *(const float4*)&eattr_perm[(size_t)en * 4];
                xl1.v = *(const bf16x8*)&xlh[((size_t)(unsigned)cA << 7) + c0];
            }
            if (en + 4 < e1) cA = col[en + 4];   // refill index pipe, 1-iter slack

            // ---- process (ea0, xl0) ----
            f32x2 xl2[4];
            #pragma unroll
            for (int p = 0; p < 4; ++p) {
                unsigned int u = xl0.u[p];
                xl2[p] = (f32x2){__uint_as_float(u << 16), __uint_as_float(u & 0xffff0000u)};
            }
            f32x2 vd = (f32x2){0.f, 0.f};
            #pragma unroll
            for (int p = 0; p < 4; ++p) {
                f32x2 z = xl2[p] + xr2[p];
                z += splat2(ea0.x) * we2[0][p];
                z += splat2(ea0.y) * we2[1][p];
                z += splat2(ea0.z) * we2[2][p];
                z += splat2(ea0.w) * we2[3][p];
                f32x2 zs = splat2(SLOPE) * z;
                f32x2 lz = (f32x2){fmaxf(z.x, zs.x), fmaxf(z.y, zs.y)};
                vd += lz * at2[p];
            }
            float v = dpp_red16(vd.x + vd.y);   // VALU-only 16-lane sum

            bool trig = (v - m > 8.0f);          // first edge: m=-inf -> true
            if (__any(trig)) {
                // wave-uniform slow path; groups not triggering get mnew==m,
                // scale==1 -> identical result, no divergence bookkeeping
                float mnew  = fmaxf(m, v);
                float scale = __expf(m - mnew);  // 0 on first edge
                float wgt   = __expf(v - mnew);
                den = den * scale + wgt;
                #pragma unroll
                for (int p = 0; p < 4; ++p)
                    acc2[p] = acc2[p] * splat2(scale) + splat2(wgt) * xl2[p];
                m = mnew;
            } else {
                float wgt = __expf(v - m);
                den += wgt;
                #pragma unroll
                for (int p = 0; p < 4; ++p) acc2[p] += splat2(wgt) * xl2[p];
            }

            if (hn) { ea0 = ea1; xl0 = xl1; }
            e = en;
        }

        // combine 4 groups (differing running maxima)
        float M = fmaxf(m, __shfl_xor(m, 16));
        M = fmaxf(M, __shfl_xor(M, 32));
        float sc = __expf(m - M);        // 0 for empty groups
        float d2 = den * sc;
        d2 += __shfl_xor(d2, 16);
        d2 += __shfl_xor(d2, 32);
        float inv = 1.f / (d2 + 1e-16f);
        float o[8];
        #pragma unroll
        for (int p = 0; p < 4; ++p) {
            float ax = acc2[p].x * sc;
            float ay = acc2[p].y * sc;
            ax += __shfl_xor(ax, 16); ax += __shfl_xor(ax, 32);
            ay += __shfl_xor(ay, 16); ay += __shfl_xor(ay, 32);
            float vx = ax * inv + bv[2 * p];
            float vy = ay * inv + bv[2 * p + 1];
            o[2 * p]     = do_relu ? fmaxf(vx, 0.f) : vx;
            o[2 * p + 1] = do_relu ? fmaxf(vy, 0.f) : vy;
        }
        if (n < N && g == 0) {
            *(float4*)&out[((size_t)n << 7) + c0]     = make_float4(o[0], o[1], o[2], o[3]);
            *(float4*)&out[((size_t)n << 7) + c0 + 4] = make_float4(o[4], o[5], o[6], o[7]);
        }
    }
}

// ---------------------------------------------------------------- launch

static inline char* carve(char*& p, size_t bytes) {
    char* r = p;
    p += (bytes + 255) & ~(size_t)255;
    return r;
}

extern "C" void kernel_launch(void* const* d_in, const int* in_sizes, int n_in,
                              void* d_out, int out_size, void* d_ws, size_t ws_size,
                              hipStream_t stream)
{
    const int* edge_index = (const int*)d_in[0];
    int E = in_sizes[0] / 2;
    int N = in_sizes[2] / 128;
    const int* srcv = edge_index;
    const int* dstv = edge_index + E;
    const float* eattr = (const float*)d_in[1];
    const float* x = (const float*)d_in[2];

    char* p = (char*)d_ws;
    int*   deg    = (int*)  carve(p, (size_t)N * 4);
    int*   fill   = (int*)  carve(p, (size_t)N * 4);
    int*   rowptr = (int*)  carve(p, (size_t)(N + 1) * 4);
    int*   bsum   = (int*)  carve(p, (size_t)1024 * 4);
    int*   col    = (int*)  carve(p, (size_t)(E + N) * 4);
    float* eperm  = (float*)carve(p, (size_t)(E + N) * 16);
    unsigned short* xlh = (unsigned short*)carve(p, (size_t)N * 256);
    unsigned short* xrh = (unsigned short*)carve(p, (size_t)N * 256);
    unsigned short* Thi = (unsigned short*)carve(p, (size_t)3 * 256 * 128 * 2);
    unsigned short* Tlo = (unsigned short*)carve(p, (size_t)3 * 256 * 128 * 2);

    hipMemsetAsync(deg,  0, (size_t)N * 4, stream);
    hipMemsetAsync(fill, 0, (size_t)N * 4, stream);

    int NB = (N + 1023) / 1024;
    count_deg_kernel<<<(E + 255) / 256, 256, 0, stream>>>(dstv, deg, E);
    scanA_kernel<<<NB, 256, 0, stream>>>(deg, bsum, N);
    scanB_kernel<<<1, 1024, 0, stream>>>(bsum, NB);
    scanC_kernel<<<NB, 256, 0, stream>>>(deg, bsum, rowptr, N);
    fill_csr_kernel<<<(E + 255) / 256, 256, 0, stream>>>(srcv, dstv, eattr, rowptr, fill, col, eperm, E);
    selfloop_kernel<<<(N + 255) / 256, 256, 0, stream>>>(rowptr, deg, col, eperm, N);

    for (int li = 0; li < 3; ++li) {
        const float* Wl = (const float*)d_in[3 + 5 * li + 0];
        const float* Wr = (const float*)d_in[3 + 5 * li + 1];
        wprep_kernel<<<256, 128, 0, stream>>>(Wl, Wr,
                                              Thi + (size_t)li * 256 * 128,
                                              Tlo + (size_t)li * 256 * 128);
    }

    float* out = (float*)d_out;
    for (int li = 0; li < 3; ++li) {
        const float* Wep = (const float*)d_in[3 + 5 * li + 2];
        const float* atp = (const float*)d_in[3 + 5 * li + 3];
        const float* bp  = (const float*)d_in[3 + 5 * li + 4];
        const float* hin = (li == 0) ? x : out;
        gemm_mfma_kernel<<<(N + 31) / 32, 256, 0, stream>>>(
            hin, Thi + (size_t)li * 256 * 128, Tlo + (size_t)li * 256 * 128, xlh, xrh, N);
        gat_agg_kernel<<<(N + 15) / 16, 256, 0, stream>>>(xlh, xrh, rowptr, col, eperm,
                                                          Wep, atp, bp, out, N, li < 2 ? 1 : 0);
    }
}